// Round 1
// baseline (348.385 us; speedup 1.0000x reference)
//
#include <hip/hip_runtime.h>

#define LL 512
#define BB 32
#define TT 48
#define KK 8
#define NSEGC 64
#define TPAD 52      // padded P row stride (dwords): rows start 4-banks apart -> b128 reads conflict-free
#define NSLOT 16     // ring slots (16 > 2*K so same-step read/write slots never collide)
#define GROW 5.0f    // normalizer growth estimate; feedback corrects any error, value non-critical

template<int CTRL>
__device__ __forceinline__ float dpp_shr_add(float x) {
  // row_shr:N within 16-lane rows, bound_ctrl=1 (zero-fill). Used for 8-lane suffix reduction.
  int r = __builtin_amdgcn_update_dpp(0, __float_as_int(x), CTRL, 0xF, 0xF, true);
  return __int_as_float(r);
}

__global__ __launch_bounds__(384, 1)
void semicrf_kernel(const float* __restrict__ E, const int* __restrict__ tags,
                    const int* __restrict__ lens, const int* __restrict__ mask,
                    const float* __restrict__ st, const float* __restrict__ et,
                    const float* __restrict__ tr, float* __restrict__ out)
{
  const int b   = blockIdx.x;      // one block per batch element
  const int tid = threadIdx.x;
  const int t   = tid >> 3;        // current-tag index 0..47
  const int d   = tid & 7;         // segment-length-1, 0..7 (contiguous in lane for DPP)

  __shared__ __align__(16) float P[NSLOT][TPAD]; // exp-normalized alpha ring
  __shared__ float Mbuf[NSLOT];                  // per-slot normalizer M_s
  __shared__ float Abuf[NSLOT];                  // per-slot residual r_s = alpha_s[0]-M_s
  __shared__ float num_sh;

  // W column in registers: w[k] = exp(trans[k][t])  (t' = k rows)
  float w[TT];
  #pragma unroll
  for (int k = 0; k < TT; ++k) w[k] = __expf(tr[k * TT + t]);
  const float st_t = st[t];

  // zero rings (slots read-before-write at startup must read as 0 -> dot=0 -> contribution 0)
  for (int i = tid; i < NSLOT * TPAD; i += 384) (&P[0][0])[i] = 0.f;
  if (tid < NSLOT) { Mbuf[tid] = 0.f; Abuf[tid] = 0.f; }

  // ---------------- numerator (wave 0 only, one lane per segment) ----------------
  if (tid < 64) {
    const int s    = tid;
    const int lenv = lens[s * BB + b];
    int pre = lenv;                         // inclusive prefix sum of lens over lanes
    #pragma unroll
    for (int off = 1; off < 64; off <<= 1) {
      int y = __shfl_up(pre, off, 64);
      if (s >= off) pre += y;
    }
    int ms = 0;                             // mask.sum(0) for this b
    #pragma unroll
    for (int kk = 0; kk < LL / 64; ++kk) ms += mask[(s + 64 * kk) * BB + b];
    #pragma unroll
    for (int off = 32; off; off >>= 1) ms += __shfl_xor(ms, off, 64);
    const int max_idx = (ms < LL - 1) ? ms : (LL - 1);
    float term;
    if (s == 0) {
      const int tag0 = tags[b];
      int i1 = lenv - 1; if (i1 < 0) i1 = 0; if (i1 > LL - 1) i1 = LL - 1;
      const float se = 0.5f * (E[b * TT + tag0] + E[(i1 * BB + b) * TT + tag0]);
      int send = ms - 1; if (send < 0) send = 0; if (send > LL - 1) send = LL - 1;
      term = st[tag0] + se + et[tags[send * BB + b]];
    } else {
      int startp = pre - lenv;              // exclusive prefix = cumsum(lens[0..s-1])
      if (startp > max_idx) startp = max_idx;
      int endp1 = startp + lenv - 1; if (endp1 > LL - 1) endp1 = LL - 1;
      int sm1 = startp - 1; if (sm1 < 0) sm1 = 0;
      const int  stg = tags[startp * BB + b];
      const int  ptg = tags[sm1 * BB + b];
      const int  etg = tags[endp1 * BB + b];
      const float m  = (float)mask[startp * BB + b];
      const float se = 0.5f * (E[(startp * BB + b) * TT + stg] + E[(endp1 * BB + b) * TT + stg]);
      term = (se + tr[ptg * TT + etg]) * m;
    }
    #pragma unroll
    for (int off = 32; off; off >>= 1) term += __shfl_xor(term, off, 64);
    if (s == 0) num_sh = term;
  }
  __syncthreads();

  // ---------------- slot 0: alpha_0 = start_t + E[0] ----------------
  const float M0 = st[0] + E[b * TT + 0];   // M_0 = alpha_0[0]; spread over t is small, fine
  if (d == 7) {
    const float a0t = st_t + E[b * TT + t];
    P[0][t] = __expf(a0t - M0);
    if (t == 0) { Mbuf[0] = M0; Abuf[0] = 0.f; }
  }
  __syncthreads();

  // ---------------- emission pipeline (prefetch 2 steps ahead, registers) ----------------
  const float* __restrict__ Eb = E + b * TT + t;   // element j at Eb[j*BB*TT]
  const int*   __restrict__ Mb = mask + b;
  int h1 = 1 - d; if (h1 < 0) h1 = 0;
  int h2 = 2 - d; if (h2 < 0) h2 = 0;
  float ecur  = Eb[1 * BB * TT];
  float ehold = Eb[h1 * BB * TT];
  float ncur  = Eb[2 * BB * TT];
  float nhold = Eb[h2 * BB * TT];
  int   mcur  = Mb[1 * BB];
  int   mnext = Mb[2 * BB];

  // ---------------- main scan: j = 1 .. 511, ONE barrier per step ----------------
  for (int j = 1; j < LL; ++j) {
    int jn = j + 2; if (jn > LL - 1) jn = LL - 1;     // prefetch index (clamped; tail values unused)
    int hn = jn - d; if (hn < 0) hn = 0;
    const float fcur  = Eb[jn * BB * TT];
    const float fhold = Eb[hn * BB * TT];
    const int   mf    = Mb[jn * BB];

    const int   slp   = (j - 1) & (NSLOT - 1);
    const float Mprev = Mbuf[slp];
    const float rprev = Abuf[slp];
    const float Mj    = Mprev + rprev + GROW;         // feedback normalizer (value non-critical)
    const int   sld   = (j - 1 - d) & (NSLOT - 1);
    const float Md    = Mbuf[sld];

    // dot(P[j-1-d], W[:,t]) : 12x ds_read_b128 (8-lane broadcast, rows tile all 32 banks)
    const float* __restrict__ prow = &P[sld][0];
    float a0 = 0.f, a1 = 0.f, a2 = 0.f, a3 = 0.f;
    #pragma unroll
    for (int q = 0; q < 12; ++q) {
      const float4 pv = *(const float4*)(prow + 4 * q);
      a0 = fmaf(pv.x, w[4 * q + 0], a0);
      a1 = fmaf(pv.y, w[4 * q + 1], a1);
      a2 = fmaf(pv.z, w[4 * q + 2], a2);
      a3 = fmaf(pv.w, w[4 * q + 3], a3);
    }
    const float dot = (a0 + a1) + (a2 + a3);
    const float seg = 0.5f * (ehold + ecur);
    float c = __expf(Md - Mj + seg) * dot;            // contribution of segment length d+1
    if (j < KK) {                                     // startup: i==0 start case; d>j auto-zero via dot=0
      if (d == j) c = __expf(st_t + seg - Mj);
    }
    // sum over d within the 8-lane group (suffix sums -> lane d==7 holds total)
    float v = c;
    v += dpp_shr_add<0x111>(v);
    v += dpp_shr_add<0x112>(v);
    v += dpp_shr_add<0x114>(v);
    if (d == 7) {
      if (mcur == 0) v = P[slp][t] * __expf(Mprev - Mj);   // masked step: alpha_j = alpha_{j-1}
      P[j & (NSLOT - 1)][t] = v;
      if (t == 0) {
        Mbuf[j & (NSLOT - 1)] = Mj;
        Abuf[j & (NSLOT - 1)] = __logf(v);            // residual feedback (accuracy non-critical)
      }
    }
    ecur = ncur; ehold = nhold; ncur = fcur; nhold = fhold;
    mcur = mnext; mnext = mf;
    __syncthreads();
  }

  // ---------------- epilogue: denom = M + log(sum P*exp(et)); llh = num - denom ----------------
  if (tid == 0) {
    const int   sl = (LL - 1) & (NSLOT - 1);
    const float Mf = Mbuf[sl];
    float s = 0.f;
    #pragma unroll
    for (int k = 0; k < TT; ++k) s += P[sl][k] * __expf(et[k]);
    atomicAdd(out, num_sh - (Mf + __logf(s)));
  }
}

extern "C" void kernel_launch(void* const* d_in, const int* in_sizes, int n_in,
                              void* d_out, int out_size, void* d_ws, size_t ws_size,
                              hipStream_t stream) {
  (void)in_sizes; (void)n_in; (void)out_size; (void)d_ws; (void)ws_size;
  const float* E    = (const float*)d_in[0];
  const int*   tags = (const int*)d_in[1];
  const int*   lens = (const int*)d_in[2];
  const int*   mask = (const int*)d_in[3];
  const float* st   = (const float*)d_in[4];
  const float* et   = (const float*)d_in[5];
  const float* tr   = (const float*)d_in[6];
  float* out = (float*)d_out;
  hipMemsetAsync(out, 0, sizeof(float), stream);
  semicrf_kernel<<<dim3(BB), dim3(384), 0, stream>>>(E, tags, lens, mask, st, et, tr, out);
}

// Round 2
// 275.421 us; speedup vs baseline: 1.2649x; 1.2649x over previous
//
#include <hip/hip_runtime.h>

#define LL 512
#define BB 32
#define TT 48
#define GROW 5.0f   // normalizer growth estimate; per-step log-feedback corrects it (value non-critical)

__device__ __forceinline__ float bcast0(float x) {
  return __int_as_float(__builtin_amdgcn_readfirstlane(__float_as_int(x)));
}

// Single wave per batch element. Exp-domain semi-CRF forward scan with one
// 48x48 matvec per step (PA_j = P_{j-1} . W) and an 8-deep register ring of
// q_i = PA_i * exp(0.5 E_i) (slot = i & 7, compile-time after unroll-8).
// alpha_j = u_j * sum_d s_d * q_{j-d}   with s_d = exp(M_{i-1} - M_j) maintained
// multiplicatively (s *= exp(-g) each step). Start case is ring slot i=0.
// No __syncthreads: P double-buffer in LDS, same-wave DS ops are in-order.
__global__ __launch_bounds__(64, 1)
void semicrf_kernel(const float* __restrict__ E, const int* __restrict__ tags,
                    const int* __restrict__ lens, const int* __restrict__ mask,
                    const float* __restrict__ st, const float* __restrict__ et,
                    const float* __restrict__ tr, float* __restrict__ out)
{
  const int b    = blockIdx.x;
  const int lane = threadIdx.x;
  const int t    = (lane < TT) ? lane : (TT - 1);   // lanes 48..63 duplicate t=47 (write-only pad slots)

  __shared__ __align__(16) float P[2][64];          // exp-normalized alpha, parity = j & 1

  // W column in registers: w[k] = exp(trans[k][t])
  float w[TT];
  #pragma unroll
  for (int k = 0; k < TT; ++k) w[k] = __expf(tr[k * TT + t]);
  const float st_t = st[t];

  // ---------------- numerator: one lane per segment (NSEG=64) ----------------
  float num;
  {
    const int s    = lane;
    const int lenv = lens[s * BB + b];
    int pre = lenv;                       // inclusive prefix sum of lens
    #pragma unroll
    for (int off = 1; off < 64; off <<= 1) {
      int y = __shfl_up(pre, off, 64);
      if (s >= off) pre += y;
    }
    int ms = 0;                           // mask.sum(0)
    #pragma unroll
    for (int kk = 0; kk < LL / 64; ++kk) ms += mask[(s + 64 * kk) * BB + b];
    #pragma unroll
    for (int off = 32; off; off >>= 1) ms += __shfl_xor(ms, off, 64);
    const int max_idx = (ms < LL - 1) ? ms : (LL - 1);
    float term;
    if (s == 0) {
      const int tag0 = tags[b];
      int i1 = lenv - 1; if (i1 < 0) i1 = 0; if (i1 > LL - 1) i1 = LL - 1;
      const float se = 0.5f * (E[b * TT + tag0] + E[(i1 * BB + b) * TT + tag0]);
      int send = ms - 1; if (send < 0) send = 0; if (send > LL - 1) send = LL - 1;
      term = st[tag0] + se + et[tags[send * BB + b]];
    } else {
      int startp = pre - lenv;
      if (startp > max_idx) startp = max_idx;
      int endp1 = startp + lenv - 1; if (endp1 > LL - 1) endp1 = LL - 1;
      int sm1 = startp - 1; if (sm1 < 0) sm1 = 0;
      const int  stg = tags[startp * BB + b];
      const int  ptg = tags[sm1 * BB + b];
      const int  etg = tags[endp1 * BB + b];
      const float m  = (float)mask[startp * BB + b];
      const float se = 0.5f * (E[(startp * BB + b) * TT + stg] + E[(endp1 * BB + b) * TT + stg]);
      term = (se + tr[ptg * TT + etg]) * m;
    }
    #pragma unroll
    for (int off = 32; off; off >>= 1) term += __shfl_xor(term, off, 64);
    num = term;                           // all lanes hold the batch numerator
  }

  // ---------------- scan init (j = 0) ----------------
  const float e0 = E[b * TT + t];
  const float M0 = bcast0(st_t + e0);     // M_0 = alpha_0[0]
  float Pcur = __expf(st_t + e0 - M0);    // P_0[t]
  P[0][lane] = Pcur;
  const float u0 = __expf(0.5f * e0);

  float qr[8], sr[8];
  #pragma unroll
  for (int p = 0; p < 8; ++p) { qr[p] = 0.f; sr[p] = 0.f; }
  qr[0] = __expf(st_t) * u0;              // start-case pseudo-entry for i = 0
  sr[0] = __expf(-M0);                    // convention Mhat_0 = 0

  float Mcur  = M0;
  float g     = GROW;                     // log(P_0[0]) = 0  -> g_1 = GROW
  float glast = 0.f;

  // prefetch chunk 0 (j = 1..8)
  float ecur[8]; int mcur_[8];
  #pragma unroll
  for (int uu = 0; uu < 8; ++uu) {
    ecur[uu]  = E[(uu + 1) * BB * TT + b * TT + t];
    mcur_[uu] = mask[(uu + 1) * BB + b];
  }

  // ---------------- main scan: 64 chunks x 8 = steps j = 1..512 ----------------
  // step 512 is a deliberate harmless overrun: clamped loads, writes P[0]
  // (epilogue reads P[1] = j=511), M_511 recovered as Mcur - glast.
  for (int c = 0; c < 64; ++c) {
    // prefetch chunk c+1 (j = 8c+9 .. 8c+16, clamped)
    float enx[8]; int mnx[8];
    #pragma unroll
    for (int uu = 0; uu < 8; ++uu) {
      int jn = 8 * c + 9 + uu; if (jn > LL - 1) jn = LL - 1;
      enx[uu] = E[jn * BB * TT + b * TT + t];
      mnx[uu] = mask[jn * BB + b];
    }
    float uch[8];
    #pragma unroll
    for (int uu = 0; uu < 8; ++uu) uch[uu] = __expf(0.5f * ecur[uu]);

    #pragma unroll
    for (int u = 0; u < 8; ++u) {
      // j = 8c + u + 1 ;  ring slot rp = j & 7 = (u+1) & 7 ; parity = (u+1) & 1
      const int rp   = (u + 1) & 7;
      const int wpar = (u + 1) & 1;

      const float Mnew = Mcur + g;               // M_j
      const float eg   = __expf(-g);             // exp(M_{j-1} - M_j)

      // matvec PA_j[t] = sum_k P_{j-1}[k] * w[k]  (broadcast LDS reads, conflict-free)
      const float* __restrict__ prow = &P[wpar ^ 1][0];
      float a0 = 0.f, a1 = 0.f, a2 = 0.f, a3 = 0.f;
      #pragma unroll
      for (int q = 0; q < 12; ++q) {
        const float4 pv = *(const float4*)(prow + 4 * q);
        a0 = fmaf(pv.x, w[4 * q + 0], a0);
        a1 = fmaf(pv.y, w[4 * q + 1], a1);
        a2 = fmaf(pv.z, w[4 * q + 2], a2);
        a3 = fmaf(pv.w, w[4 * q + 3], a3);
      }
      const float PA = (a0 + a1) + (a2 + a3);
      const float uj = uch[u];

      // ring update (all indices compile-time)
      #pragma unroll
      for (int p = 0; p < 8; ++p) sr[p] *= eg;
      sr[rp] = eg;
      qr[rp] = PA * uj;

      // combine over segment lengths d = 0..7  (slot (j-d) & 7)
      float v = 0.f;
      #pragma unroll
      for (int d = 0; d < 8; ++d) v = fmaf(sr[(rp - d) & 7], qr[(rp - d) & 7], v);
      v *= uj;

      if (mcur_[u] == 0) v = Pcur * eg;          // masked: alpha_j = alpha_{j-1}

      Pcur = v;
      P[wpar][lane] = v;
      const float v0 = bcast0(v);                // lane 0 = tag 0
      glast = g;
      g     = __logf(v0) + GROW;                 // feedback normalizer (non-critical accuracy)
      Mcur  = Mnew;
    }

    #pragma unroll
    for (int uu = 0; uu < 8; ++uu) { ecur[uu] = enx[uu]; mcur_[uu] = mnx[uu]; }
  }

  // ---------------- epilogue ----------------
  // denom = M_511 + log( sum_t P_511[t] * exp(et[t]) )
  {
    const float Mf = Mcur - glast;               // undo step-512 update
    float vv = (lane < TT) ? P[1][lane] * __expf(et[lane]) : 0.f;
    #pragma unroll
    for (int off = 32; off; off >>= 1) vv += __shfl_xor(vv, off, 64);
    if (lane == 0) atomicAdd(out, num - (Mf + __logf(vv)));
  }
}

extern "C" void kernel_launch(void* const* d_in, const int* in_sizes, int n_in,
                              void* d_out, int out_size, void* d_ws, size_t ws_size,
                              hipStream_t stream) {
  (void)in_sizes; (void)n_in; (void)out_size; (void)d_ws; (void)ws_size;
  const float* E    = (const float*)d_in[0];
  const int*   tags = (const int*)d_in[1];
  const int*   lens = (const int*)d_in[2];
  const int*   mask = (const int*)d_in[3];
  const float* st   = (const float*)d_in[4];
  const float* et   = (const float*)d_in[5];
  const float* tr   = (const float*)d_in[6];
  float* out = (float*)d_out;
  hipMemsetAsync(out, 0, sizeof(float), stream);
  semicrf_kernel<<<dim3(BB), dim3(64), 0, stream>>>(E, tags, lens, mask, st, et, tr, out);
}

// Round 3
// 170.145 us; speedup vs baseline: 2.0476x; 1.6187x over previous
//
#include <hip/hip_runtime.h>

#define LL 512
#define BB 32
#define TT 48
#define GROW 5.0f   // normalizer growth estimate; per-step log-feedback corrects it (value non-critical)

typedef _Float16 half2_t __attribute__((ext_vector_type(2)));

__device__ __forceinline__ float bcast0(float x) {
  return __int_as_float(__builtin_amdgcn_readfirstlane(__float_as_int(x)));
}

#if __has_builtin(__builtin_amdgcn_fdot2)
__device__ __forceinline__ float fdot2(half2_t a, half2_t b, float c) {
  return __builtin_amdgcn_fdot2(a, b, c, false);
}
#else
__device__ __forceinline__ float fdot2(half2_t a, half2_t b, float c) {
  return c + (float)a.x * (float)b.x + (float)a.y * (float)b.y;
}
#endif

#define H2(x) __builtin_bit_cast(half2_t, (x))

// One wave per batch element; no barriers (same-wave DS ops are in-order).
// Exp-domain semi-CRF scan: one 48x48 matvec per step (f16 dot2 pairs),
// 8-deep register ring Qr of scaled segment-start terms, scalar log-feedback
// normalizer. Emissions pre-transformed to u=exp(0.5E) in LDS; P ring in LDS
// as f16 (6x ds_read_b128 broadcast per step).
__global__ __launch_bounds__(64, 1)
void semicrf_kernel(const float* __restrict__ E, const int* __restrict__ tags,
                    const int* __restrict__ lens, const int* __restrict__ mask,
                    const float* __restrict__ st, const float* __restrict__ et,
                    const float* __restrict__ tr, float* __restrict__ out)
{
  const int b    = blockIdx.x;
  const int lane = threadIdx.x;
  const int t    = (lane < TT) ? lane : (TT - 1);   // pad lanes duplicate t=47

  __shared__ __align__(16) float    U[LL * TT];     // u_j[t] = exp(0.5*E[j][b][t])  (declared FIRST: step-512 overrun stays in-block)
  __shared__              int       Msk[LL];
  __shared__ __align__(16) _Float16 Ph[2][64];      // f16 P double buffer, parity = j & 1

  // ---------------- numerator: one lane per segment (NSEG=64) ----------------
  float num;
  {
    const int s    = lane;
    const int lenv = lens[s * BB + b];
    int pre = lenv;                       // inclusive prefix sum of lens
    #pragma unroll
    for (int off = 1; off < 64; off <<= 1) {
      int y = __shfl_up(pre, off, 64);
      if (s >= off) pre += y;
    }
    int ms = 0;                           // mask.sum(0)
    #pragma unroll
    for (int kk = 0; kk < LL / 64; ++kk) ms += mask[(s + 64 * kk) * BB + b];
    #pragma unroll
    for (int off = 32; off; off >>= 1) ms += __shfl_xor(ms, off, 64);
    const int max_idx = (ms < LL - 1) ? ms : (LL - 1);
    float term;
    if (s == 0) {
      const int tag0 = tags[b];
      int i1 = lenv - 1; if (i1 < 0) i1 = 0; if (i1 > LL - 1) i1 = LL - 1;
      const float se = 0.5f * (E[b * TT + tag0] + E[(i1 * BB + b) * TT + tag0]);
      int send = ms - 1; if (send < 0) send = 0; if (send > LL - 1) send = LL - 1;
      term = st[tag0] + se + et[tags[send * BB + b]];
    } else {
      int startp = pre - lenv;
      if (startp > max_idx) startp = max_idx;
      int endp1 = startp + lenv - 1; if (endp1 > LL - 1) endp1 = LL - 1;
      int sm1 = startp - 1; if (sm1 < 0) sm1 = 0;
      const int  stg = tags[startp * BB + b];
      const int  ptg = tags[sm1 * BB + b];
      const int  etg = tags[endp1 * BB + b];
      const float m  = (float)mask[startp * BB + b];
      const float se = 0.5f * (E[(startp * BB + b) * TT + stg] + E[(endp1 * BB + b) * TT + stg]);
      term = (se + tr[ptg * TT + etg]) * m;
    }
    #pragma unroll
    for (int off = 32; off; off >>= 1) term += __shfl_xor(term, off, 64);
    num = term;
  }

  // ---------------- W column as 24 packed f16 pairs, PINNED in VGPRs ----------------
  unsigned int w2[24];
  #pragma unroll
  for (int p = 0; p < 24; ++p) {
    half2_t h;
    h.x = (_Float16)__expf(tr[(2 * p) * TT + t]);
    h.y = (_Float16)__expf(tr[(2 * p + 1) * TT + t]);
    w2[p] = __builtin_bit_cast(unsigned int, h);
  }
  #pragma unroll
  for (int p = 0; p < 24; ++p) asm volatile("" : "+v"(w2[p]));  // block rematerialization/sinking

  // ---------------- stage u = exp(0.5 E) and mask into LDS ----------------
  if (lane < TT) {
    const int jj = lane / 12;            // 4 rows per pass, 12 lanes x float4 per row
    const int tq = (lane % 12) * 4;
    const float* __restrict__ src = E + (size_t)(jj * BB + b) * TT + tq;
    float* dst = U + jj * TT + tq;
    #pragma unroll 4
    for (int gI = 0; gI < LL / 4; ++gI) {
      const float4 ev = *(const float4*)(src + (size_t)gI * 4 * BB * TT);
      float4 uv;
      uv.x = __expf(0.5f * ev.x);
      uv.y = __expf(0.5f * ev.y);
      uv.z = __expf(0.5f * ev.z);
      uv.w = __expf(0.5f * ev.w);
      *(float4*)(dst + gI * 4 * TT) = uv;
    }
  }
  for (int i = lane; i < LL; i += 64) Msk[i] = mask[i * BB + b];

  // ---------------- scan init (j = 0) ----------------
  const float st_t = st[t];
  const float e0   = E[b * TT + t];
  const float M0   = bcast0(st_t + e0);            // lane 0: st[0] + E[0][b][0]
  float Pcur = __expf(st_t + e0 - M0);
  Ph[0][lane] = (_Float16)Pcur;

  float Qr[8];                                     // Qr[p] = s_p * q_p (scale folded in)
  #pragma unroll
  for (int p = 0; p < 8; ++p) Qr[p] = 0.f;
  Qr[0] = __expf(st_t - M0) * __expf(0.5f * e0);   // start-case pseudo-entry i=0

  float Mcur  = M0;
  float g     = GROW;                              // log(P_0[0]) = 0
  float glast = 0.f;

  // ---------------- main scan: 64 chunks x 8 = steps j = 1..512 ----------------
  // step 512 is a harmless overrun: reads in-block garbage, writes parity 0;
  // epilogue reads parity 1 (j=511); M_511 = Mcur - glast.
  for (int c = 0; c < 64; ++c) {
    #pragma unroll
    for (int u = 0; u < 8; ++u) {
      const int j    = 8 * c + u + 1;
      const int rp   = (u + 1) & 7;                // ring slot (compile-time)
      const int wpar = (u + 1) & 1;                // write parity (compile-time)

      const float uj   = U[j * TT + t];            // broadcast-friendly LDS reads
      const int   mj   = Msk[j];
      const float Mnew = Mcur + g;
      const float eg   = __expf(-g);               // exp(M_{j-1} - M_j)

      // matvec PA[t] = sum_k P_{j-1}[k] * w[k][t]  — 6x b128 broadcast + 24x dot2
      const float4 q0 = *(const float4*)&Ph[wpar ^ 1][0];
      const float4 q1 = *(const float4*)&Ph[wpar ^ 1][8];
      const float4 q2 = *(const float4*)&Ph[wpar ^ 1][16];
      const float4 q3 = *(const float4*)&Ph[wpar ^ 1][24];
      const float4 q4 = *(const float4*)&Ph[wpar ^ 1][32];
      const float4 q5 = *(const float4*)&Ph[wpar ^ 1][40];
      float a0 = 0.f, a1 = 0.f, a2 = 0.f, a3 = 0.f;
      a0 = fdot2(H2(q0.x), H2(w2[0]),  a0);
      a1 = fdot2(H2(q0.y), H2(w2[1]),  a1);
      a2 = fdot2(H2(q0.z), H2(w2[2]),  a2);
      a3 = fdot2(H2(q0.w), H2(w2[3]),  a3);
      a0 = fdot2(H2(q1.x), H2(w2[4]),  a0);
      a1 = fdot2(H2(q1.y), H2(w2[5]),  a1);
      a2 = fdot2(H2(q1.z), H2(w2[6]),  a2);
      a3 = fdot2(H2(q1.w), H2(w2[7]),  a3);
      a0 = fdot2(H2(q2.x), H2(w2[8]),  a0);
      a1 = fdot2(H2(q2.y), H2(w2[9]),  a1);
      a2 = fdot2(H2(q2.z), H2(w2[10]), a2);
      a3 = fdot2(H2(q2.w), H2(w2[11]), a3);
      a0 = fdot2(H2(q3.x), H2(w2[12]), a0);
      a1 = fdot2(H2(q3.y), H2(w2[13]), a1);
      a2 = fdot2(H2(q3.z), H2(w2[14]), a2);
      a3 = fdot2(H2(q3.w), H2(w2[15]), a3);
      a0 = fdot2(H2(q4.x), H2(w2[16]), a0);
      a1 = fdot2(H2(q4.y), H2(w2[17]), a1);
      a2 = fdot2(H2(q4.z), H2(w2[18]), a2);
      a3 = fdot2(H2(q4.w), H2(w2[19]), a3);
      a0 = fdot2(H2(q5.x), H2(w2[20]), a0);
      a1 = fdot2(H2(q5.y), H2(w2[21]), a1);
      a2 = fdot2(H2(q5.z), H2(w2[22]), a2);
      a3 = fdot2(H2(q5.w), H2(w2[23]), a3);
      const float PA = (a0 + a1) + (a2 + a3);

      // ring update (all indices compile-time) + depth-3 combine tree
      #pragma unroll
      for (int p = 0; p < 8; ++p)
        Qr[p] = (p == rp) ? (eg * PA) * uj : Qr[p] * eg;
      float v = ((Qr[0] + Qr[1]) + (Qr[2] + Qr[3])) + ((Qr[4] + Qr[5]) + (Qr[6] + Qr[7]));
      v *= uj;

      const float vm = Pcur * eg;                  // masked: alpha_j = alpha_{j-1}
      v = mj ? v : vm;

      Pcur = v;
      Ph[wpar][lane] = (_Float16)v;                // lanes 48-63 write pad slots (never read)
      const float v0 = bcast0(v);                  // lane 0 = tag 0
      glast = g;
      g     = __logf(v0) + GROW;                   // feedback normalizer
      Mcur  = Mnew;
    }
  }

  // ---------------- epilogue: denom = M_511 + log(sum P*exp(et)) ----------------
  {
    const float Mf = Mcur - glast;
    float vv = (lane < TT) ? (float)Ph[1][lane] * __expf(et[t]) : 0.f;
    #pragma unroll
    for (int off = 32; off; off >>= 1) vv += __shfl_xor(vv, off, 64);
    if (lane == 0) atomicAdd(out, num - (Mf + __logf(vv)));
  }
}

extern "C" void kernel_launch(void* const* d_in, const int* in_sizes, int n_in,
                              void* d_out, int out_size, void* d_ws, size_t ws_size,
                              hipStream_t stream) {
  (void)in_sizes; (void)n_in; (void)out_size; (void)d_ws; (void)ws_size;
  const float* E    = (const float*)d_in[0];
  const int*   tags = (const int*)d_in[1];
  const int*   lens = (const int*)d_in[2];
  const int*   mask = (const int*)d_in[3];
  const float* st   = (const float*)d_in[4];
  const float* et   = (const float*)d_in[5];
  const float* tr   = (const float*)d_in[6];
  float* out = (float*)d_out;
  hipMemsetAsync(out, 0, sizeof(float), stream);
  semicrf_kernel<<<dim3(BB), dim3(64), 0, stream>>>(E, tags, lens, mask, st, et, tr, out);
}